// Round 2
// baseline (902.912 us; speedup 1.0000x reference)
//
#include <hip/hip_runtime.h>

#define NT   384   // 6 waves: phase-1 tasks = 32*36/384 = exactly 3 per thread
#define SPB  32    // samples per block
#define LSTR 388   // LDS row stride (floats): 16B-aligned rows, float2-aligned segments

__global__ __launch_bounds__(NT, 3)
void lila_fused(const float* __restrict__ inp,
                const float* __restrict__ W1, const float* __restrict__ b1,
                const float* __restrict__ W2, const float* __restrict__ b2,
                const float* __restrict__ W3, const float* __restrict__ b3,
                const float* __restrict__ V1, const float* __restrict__ c1,
                const float* __restrict__ V2, const float* __restrict__ c2,
                const float* __restrict__ V3, const float* __restrict__ c3,
                float* __restrict__ out)
{
    // Region A (49,664 B): input staging in phase 1; overlaid by V1(18,560)+V2(4,096) in phase 2.
    // Total LDS = 49,664 + 18,944 + 4,224 = 72,832 B -> 2 blocks/CU -> 12 waves/CU.
    __shared__ __align__(16) float lbufA[SPB * LSTR];
    __shared__ __align__(16) float lsight[SPB * 148];
    __shared__ __align__(16) float le1[SPB * 33];

    const int tid = threadIdx.x;
    const int s0  = blockIdx.x * SPB;

    // ---- stage inputs: coalesced global -> LDS (each byte fetched once) ----
    {
        const float* g = inp + (size_t)s0 * 385;
        for (int r = 0; r < SPB; ++r) {
            for (int i = tid; i < 385; i += NT)
                lbufA[r * LSTR + i] = g[r * 385 + i];
        }
    }
    __syncthreads();

    // ---- phase 1: (sample, window): 54 -> 12 -> 12 -> 4, inputs from LDS ----
    for (int t = tid; t < SPB * 36; t += NT) {
        const int s = t / 36;
        const int w = t - s * 36;
        const int x = w / 6;
        const int y = w - x * 6;
        const float* rowp = &lbufA[s * LSTR + x * 48 + y * 6];

        float win[54];
        #pragma unroll
        for (int ox = 0; ox < 3; ++ox) {
            const float2* p2 = (const float2*)(rowp + ox * 48);  // even float offset -> 8B aligned
            #pragma unroll
            for (int j = 0; j < 9; ++j) {
                const float2 v = p2[j];
                win[ox * 18 + 2 * j]     = v.x;
                win[ox * 18 + 2 * j + 1] = v.y;
            }
        }

        float h[12];
        #pragma unroll
        for (int n = 0; n < 12; ++n) h[n] = b1[n];
        #pragma unroll
        for (int k = 0; k < 54; ++k) {
            const float wk = win[k];
            #pragma unroll
            for (int n = 0; n < 12; ++n)
                h[n] = fmaf(wk, W1[k * 12 + n], h[n]);   // uniform index -> s_load stream
        }
        #pragma unroll
        for (int n = 0; n < 12; ++n) h[n] = fminf(fmaxf(h[n], -1.f), 1.f);

        float h2[12];
        #pragma unroll
        for (int n = 0; n < 12; ++n) h2[n] = b2[n];
        #pragma unroll
        for (int k = 0; k < 12; ++k) {
            const float hk = h[k];
            #pragma unroll
            for (int n = 0; n < 12; ++n)
                h2[n] = fmaf(hk, W2[k * 12 + n], h2[n]);
        }
        #pragma unroll
        for (int n = 0; n < 12; ++n) h2[n] = fminf(fmaxf(h2[n], -1.f), 1.f);

        float sg[4];
        #pragma unroll
        for (int n = 0; n < 4; ++n) sg[n] = b3[n];
        #pragma unroll
        for (int k = 0; k < 12; ++k) {
            const float hk = h2[k];
            #pragma unroll
            for (int n = 0; n < 4; ++n)
                sg[n] = fmaf(hk, W3[k * 4 + n], sg[n]);
        }
        #pragma unroll
        for (int n = 0; n < 4; ++n)
            lsight[s * 148 + w * 4 + n] = fminf(fmaxf(sg[n], -1.f), 1.f);
    }
    __syncthreads();

    // ---- overlay-stage V1, V2 into region A ----
    {
        float4*       dst = (float4*)lbufA;
        const float4* v1g = (const float4*)V1;
        for (int i = tid; i < (145 * 32) / 4; i += NT) dst[i] = v1g[i];
        const float4* v2g = (const float4*)V2;
        for (int i = tid; i < (32 * 32) / 4; i += NT) dst[(145 * 32) / 4 + i] = v2g[i];
    }
    __syncthreads();

    const float* lv1 = lbufA;              // 145*32
    const float* lw2 = lbufA + 145 * 32;   // 32*32

    // ---- phase 2: head 145 -> 32 -> 32 -> 1; 8 threads/sample x 4 channels ----
    if (tid < 8 * SPB) {
        const int s  = tid >> 3;
        const int c0 = (tid & 7) * 4;
        const float lastv = inp[(size_t)(s0 + s) * 385 + 384];

        float4 e = *(const float4*)(c1 + c0);
        const float* sgp = lsight + s * 148;
        #pragma unroll 4
        for (int r4 = 0; r4 < 36; ++r4) {
            const float4 sv = *(const float4*)(sgp + r4 * 4);
            const float svv[4] = {sv.x, sv.y, sv.z, sv.w};
            #pragma unroll
            for (int j = 0; j < 4; ++j) {
                const float v = svv[j];
                const float4 wv = *(const float4*)(lv1 + (r4 * 4 + j) * 32 + c0);
                e.x = fmaf(v, wv.x, e.x);
                e.y = fmaf(v, wv.y, e.y);
                e.z = fmaf(v, wv.z, e.z);
                e.w = fmaf(v, wv.w, e.w);
            }
        }
        {
            const float4 wv = *(const float4*)(lv1 + 144 * 32 + c0);
            e.x = fmaf(lastv, wv.x, e.x);
            e.y = fmaf(lastv, wv.y, e.y);
            e.z = fmaf(lastv, wv.z, e.z);
            e.w = fmaf(lastv, wv.w, e.w);
        }
        e.x = fminf(fmaxf(e.x, -1.f), 1.f);
        e.y = fminf(fmaxf(e.y, -1.f), 1.f);
        e.z = fminf(fmaxf(e.z, -1.f), 1.f);
        e.w = fminf(fmaxf(e.w, -1.f), 1.f);

        le1[s * 33 + c0 + 0] = e.x;
        le1[s * 33 + c0 + 1] = e.y;
        le1[s * 33 + c0 + 2] = e.z;
        le1[s * 33 + c0 + 3] = e.w;
    }
    __syncthreads();

    if (tid < 8 * SPB) {
        const int s  = tid >> 3;
        const int c0 = (tid & 7) * 4;

        float4 f = *(const float4*)(c2 + c0);
        #pragma unroll
        for (int r = 0; r < 32; ++r) {
            const float v = le1[s * 33 + r];
            const float4 wv = *(const float4*)(lw2 + r * 32 + c0);
            f.x = fmaf(v, wv.x, f.x);
            f.y = fmaf(v, wv.y, f.y);
            f.z = fmaf(v, wv.z, f.z);
            f.w = fmaf(v, wv.w, f.w);
        }
        f.x = fminf(fmaxf(f.x, -1.f), 1.f);
        f.y = fminf(fmaxf(f.y, -1.f), 1.f);
        f.z = fminf(fmaxf(f.z, -1.f), 1.f);
        f.w = fminf(fmaxf(f.w, -1.f), 1.f);

        const float4 v3 = *(const float4*)(V3 + c0);
        float part = f.x * v3.x + f.y * v3.y + f.z * v3.z + f.w * v3.w;
        part += __shfl_xor(part, 1);
        part += __shfl_xor(part, 2);
        part += __shfl_xor(part, 4);
        if ((tid & 7) == 0)
            out[s0 + s] = fminf(fmaxf(part + c3[0], -1.f), 1.f);
    }
}

extern "C" void kernel_launch(void* const* d_in, const int* in_sizes, int n_in,
                              void* d_out, int out_size, void* d_ws, size_t ws_size,
                              hipStream_t stream) {
    const float* inp = (const float*)d_in[0];
    const float* W1  = (const float*)d_in[1];
    const float* b1  = (const float*)d_in[2];
    const float* W2  = (const float*)d_in[3];
    const float* b2  = (const float*)d_in[4];
    const float* W3  = (const float*)d_in[5];
    const float* b3  = (const float*)d_in[6];
    const float* V1  = (const float*)d_in[7];
    const float* c1  = (const float*)d_in[8];
    const float* V2  = (const float*)d_in[9];
    const float* c2  = (const float*)d_in[10];
    const float* V3  = (const float*)d_in[11];
    const float* c3  = (const float*)d_in[12];
    float* out = (float*)d_out;

    const int Btot   = in_sizes[0] / 385;   // 131072
    const int blocks = Btot / SPB;          // 4096

    lila_fused<<<dim3(blocks), dim3(NT), 0, stream>>>(
        inp, W1, b1, W2, b2, W3, b3, V1, c1, V2, c2, V3, c3, out);
}

// Round 4
// 362.381 us; speedup vs baseline: 2.4916x; 2.4916x over previous
//
#include <hip/hip_runtime.h>
#include <hip/hip_bf16.h>

#define NT   384          // 6 waves
#define SPB  32           // samples per block -> 1152 rows = 72 MFMA 16-row tiles
#define LSTR 386          // fp16 elements per sample row in LDS (even, bank-spread)
#define LPAD 64           // safety pad for masked (invalid-k) gathers

typedef __attribute__((ext_vector_type(4))) float     f32x4;
typedef __attribute__((ext_vector_type(8))) _Float16  f16x8;
typedef __attribute__((ext_vector_type(4))) _Float16  f16x4;

union U8 { f16x8 v; unsigned u[4]; };
union U4 { f16x4 v; unsigned u[2]; };

static __device__ inline unsigned pack_f16(float a, float b) {
    union { _Float16 h[2]; unsigned u; } c;
    c.h[0] = (_Float16)a; c.h[1] = (_Float16)b;
    return c.u;
}
static __device__ inline void split_pack(float a, float b, unsigned& hi, unsigned& lo) {
    const _Float16 ah = (_Float16)a, bh = (_Float16)b;
    hi = pack_f16((float)ah, (float)bh);
    lo = pack_f16(a - (float)ah, b - (float)bh);
}
static __device__ inline unsigned short to_f16u(float a) {
    union { _Float16 h; unsigned short u; } c;
    c.h = (_Float16)a;
    return c.u;
}
static __device__ inline float clamp1(float v) { return fminf(fmaxf(v, -1.f), 1.f); }

static __device__ inline f32x4 mfma32(f16x8 a, f16x8 b, f32x4 c) {
    return __builtin_amdgcn_mfma_f32_16x16x32_f16(a, b, c, 0, 0, 0);
}
static __device__ inline f32x4 mfma16(f16x4 a, f16x4 b, f32x4 c) {
#if __has_builtin(__builtin_amdgcn_mfma_f32_16x16x16f16)
    return __builtin_amdgcn_mfma_f32_16x16x16f16(a, b, c, 0, 0, 0);
#else
    f32x4 d;
    asm volatile("v_mfma_f32_16x16x16_f16 %0, %1, %2, %3\n\ts_nop 7\n\ts_nop 1"
                 : "=v"(d) : "v"(a), "v"(b), "v"(c));
    return d;
#endif
}

__global__ __launch_bounds__(NT, 4)
void lila_fused(const float* __restrict__ inp,
                const float* __restrict__ W1, const float* __restrict__ b1,
                const float* __restrict__ W2, const float* __restrict__ b2,
                const float* __restrict__ W3, const float* __restrict__ b3,
                const float* __restrict__ V1, const float* __restrict__ c1,
                const float* __restrict__ V2, const float* __restrict__ c2,
                const float* __restrict__ V3, const float* __restrict__ c3,
                float* __restrict__ out)
{
    // LDS: 24,832 + 18,944 + 4,224 = 48,000 B -> 3 blocks/CU -> 18 waves/CU
    __shared__ __align__(16) unsigned short lbuf16[SPB * LSTR + LPAD]; // fp16 inputs; fp32 V1/V2 overlay in phase 2
    __shared__ __align__(16) float lsight[SPB * 148];
    __shared__ __align__(16) float le1[SPB * 33];

    const int tid  = threadIdx.x;
    const int lid  = tid & 63;
    const int wv   = tid >> 6;
    const int quad = lid >> 4;
    const int c16  = lid & 15;
    const int s0   = blockIdx.x * SPB;

    // ---- per-lane static fragments (hi + lo fp16 split of exact fp32 weights) ----
    U8 wa1h[2], wa1l[2];
    #pragma unroll
    for (int f = 0; f < 2; ++f)
        #pragma unroll
        for (int j2 = 0; j2 < 4; ++j2) {
            const int k0 = f * 32 + quad * 8 + 2 * j2;
            const float v0 = (k0     < 54 && c16 < 12) ? W1[k0 * 12 + c16]       : 0.f;
            const float v1 = (k0 + 1 < 54 && c16 < 12) ? W1[(k0 + 1) * 12 + c16] : 0.f;
            split_pack(v0, v1, wa1h[f].u[j2], wa1l[f].u[j2]);
        }
    U4 wa2h, wa2l, wa3h, wa3l;
    #pragma unroll
    for (int j2 = 0; j2 < 2; ++j2) {
        const int k0 = quad * 4 + 2 * j2;
        const float a0 = (k0     < 12 && c16 < 12) ? W2[k0 * 12 + c16]       : 0.f;
        const float a1 = (k0 + 1 < 12 && c16 < 12) ? W2[(k0 + 1) * 12 + c16] : 0.f;
        split_pack(a0, a1, wa2h.u[j2], wa2l.u[j2]);
        const float g0 = (k0     < 12 && c16 < 4) ? W3[k0 * 4 + c16]       : 0.f;
        const float g1 = (k0 + 1 < 12 && c16 < 4) ? W3[(k0 + 1) * 4 + c16] : 0.f;
        split_pack(g0, g1, wa3h.u[j2], wa3l.u[j2]);
    }
    float b1v[4], b2v[4], b3v[4];
    #pragma unroll
    for (int r = 0; r < 4; ++r) {
        const int c = quad * 4 + r;
        b1v[r] = (c < 12) ? b1[c] : 0.f;
        b2v[r] = (c < 12) ? b2[c] : 0.f;
        b3v[r] = (c < 4)  ? b3[c] : 0.f;
    }
    // gather descriptors: pair p -> k = (p>>2)*32 + quad*8 + 2*(p&3)
    int dofs[8]; unsigned msk[8];
    #pragma unroll
    for (int p = 0; p < 8; ++p) {
        const int k = (p >> 2) * 32 + quad * 8 + 2 * (p & 3);
        dofs[p] = (k / 18) * 48 + (k % 18);
        msk[p]  = (k < 54) ? 0xFFFFFFFFu : 0u;
    }

    // ---- stage inputs -> LDS as fp16 (coalesced; element 384 not needed by windows) ----
    {
        const float* g = inp + (size_t)s0 * 385;
        #pragma unroll 4
        for (int r = 0; r < SPB; ++r)
            lbuf16[r * LSTR + tid] = to_f16u(g[r * 385 + tid]);
    }
    __syncthreads();

    // ---- phase 1: per 16-row tile: D1 = W1^T*win^T -> D2 = W2^T*h -> D3 = W3^T*h2 ----
    const f32x4 z = {0.f, 0.f, 0.f, 0.f};
    for (int t = wv; t < (SPB * 36) / 16; t += NT / 64) {
        const int r = t * 16 + c16;              // row id = s*36 + w
        const int s = r / 36;
        const int w = r - s * 36;
        const int x = w / 6;
        const int y = w - x * 6;
        const int base = s * LSTR + x * 48 + y * 6;

        U8 bw[2];
        #pragma unroll
        for (int p = 0; p < 8; ++p) {
            unsigned v = *(const unsigned*)(&lbuf16[base + dofs[p]]);
            bw[p >> 2].u[p & 3] = v & msk[p];
        }

        f32x4 acc = z;
        acc = mfma32(wa1h[0].v, bw[0].v, acc);
        acc = mfma32(wa1h[1].v, bw[1].v, acc);
        acc = mfma32(wa1l[0].v, bw[0].v, acc);
        acc = mfma32(wa1l[1].v, bw[1].v, acc);

        U4 bb2;
        bb2.u[0] = pack_f16(clamp1(acc[0] + b1v[0]), clamp1(acc[1] + b1v[1]));
        bb2.u[1] = pack_f16(clamp1(acc[2] + b1v[2]), clamp1(acc[3] + b1v[3]));
        f32x4 d2 = mfma16(wa2h.v, bb2.v, z);
        d2 = mfma16(wa2l.v, bb2.v, d2);

        U4 bb3;
        bb3.u[0] = pack_f16(clamp1(d2[0] + b2v[0]), clamp1(d2[1] + b2v[1]));
        bb3.u[1] = pack_f16(clamp1(d2[2] + b2v[2]), clamp1(d2[3] + b2v[3]));
        f32x4 d3 = mfma16(wa3h.v, bb3.v, z);
        d3 = mfma16(wa3l.v, bb3.v, d3);

        if (lid < 16) {                           // quad0 holds sight channels 0..3 for row r
            f32x4 q = { clamp1(d3[0] + b3v[0]), clamp1(d3[1] + b3v[1]),
                        clamp1(d3[2] + b3v[2]), clamp1(d3[3] + b3v[3]) };
            *(f32x4*)&lsight[s * 148 + w * 4] = q;
        }
    }
    __syncthreads();

    // ---- overlay-stage V1, V2 (fp32) into the staging region ----
    {
        float4*       dst = (float4*)lbuf16;
        const float4* v1g = (const float4*)V1;
        for (int i = tid; i < (145 * 32) / 4; i += NT) dst[i] = v1g[i];
        const float4* v2g = (const float4*)V2;
        for (int i = tid; i < (32 * 32) / 4; i += NT) dst[(145 * 32) / 4 + i] = v2g[i];
    }
    __syncthreads();

    const float* lv1 = (const float*)lbuf16;
    const float* lw2 = lv1 + 145 * 32;

    // ---- phase 2: head 145 -> 32 -> 32 -> 1; 8 threads/sample x 4 channels ----
    if (tid < 8 * SPB) {
        const int s  = tid >> 3;
        const int c0 = (tid & 7) * 4;
        const float lastv = inp[(size_t)(s0 + s) * 385 + 384];

        float4 e = *(const float4*)(c1 + c0);
        const float* sgp = lsight + s * 148;
        #pragma unroll 4
        for (int r4 = 0; r4 < 36; ++r4) {
            const float4 sv = *(const float4*)(sgp + r4 * 4);
            const float svv[4] = {sv.x, sv.y, sv.z, sv.w};
            #pragma unroll
            for (int j = 0; j < 4; ++j) {
                const float v = svv[j];
                const float4 wv4 = *(const float4*)(lv1 + (r4 * 4 + j) * 32 + c0);
                e.x = fmaf(v, wv4.x, e.x);
                e.y = fmaf(v, wv4.y, e.y);
                e.z = fmaf(v, wv4.z, e.z);
                e.w = fmaf(v, wv4.w, e.w);
            }
        }
        {
            const float4 wv4 = *(const float4*)(lv1 + 144 * 32 + c0);
            e.x = fmaf(lastv, wv4.x, e.x);
            e.y = fmaf(lastv, wv4.y, e.y);
            e.z = fmaf(lastv, wv4.z, e.z);
            e.w = fmaf(lastv, wv4.w, e.w);
        }
        le1[s * 33 + c0 + 0] = clamp1(e.x);
        le1[s * 33 + c0 + 1] = clamp1(e.y);
        le1[s * 33 + c0 + 2] = clamp1(e.z);
        le1[s * 33 + c0 + 3] = clamp1(e.w);
    }
    __syncthreads();

    if (tid < 8 * SPB) {
        const int s  = tid >> 3;
        const int c0 = (tid & 7) * 4;

        float4 f = *(const float4*)(c2 + c0);
        #pragma unroll
        for (int r = 0; r < 32; ++r) {
            const float v = le1[s * 33 + r];
            const float4 wv4 = *(const float4*)(lw2 + r * 32 + c0);
            f.x = fmaf(v, wv4.x, f.x);
            f.y = fmaf(v, wv4.y, f.y);
            f.z = fmaf(v, wv4.z, f.z);
            f.w = fmaf(v, wv4.w, f.w);
        }
        f.x = clamp1(f.x);
        f.y = clamp1(f.y);
        f.z = clamp1(f.z);
        f.w = clamp1(f.w);

        const float4 v3 = *(const float4*)(V3 + c0);
        float part = f.x * v3.x + f.y * v3.y + f.z * v3.z + f.w * v3.w;
        part += __shfl_xor(part, 1);
        part += __shfl_xor(part, 2);
        part += __shfl_xor(part, 4);
        if ((tid & 7) == 0)
            out[s0 + s] = clamp1(part + c3[0]);
    }
}

extern "C" void kernel_launch(void* const* d_in, const int* in_sizes, int n_in,
                              void* d_out, int out_size, void* d_ws, size_t ws_size,
                              hipStream_t stream) {
    const float* inp = (const float*)d_in[0];
    const float* W1  = (const float*)d_in[1];
    const float* b1  = (const float*)d_in[2];
    const float* W2  = (const float*)d_in[3];
    const float* b2  = (const float*)d_in[4];
    const float* W3  = (const float*)d_in[5];
    const float* b3  = (const float*)d_in[6];
    const float* V1  = (const float*)d_in[7];
    const float* c1  = (const float*)d_in[8];
    const float* V2  = (const float*)d_in[9];
    const float* c2  = (const float*)d_in[10];
    const float* V3  = (const float*)d_in[11];
    const float* c3  = (const float*)d_in[12];
    float* out = (float*)d_out;

    const int Btot   = in_sizes[0] / 385;   // 131072
    const int blocks = Btot / SPB;          // 4096

    lila_fused<<<dim3(blocks), dim3(NT), 0, stream>>>(
        inp, W1, b1, W2, b2, W3, b3, V1, c1, V2, c2, V3, c3, out);
}